// Round 1
// baseline (463.983 us; speedup 1.0000x reference)
//
#include <hip/hip_runtime.h>

// Problem constants
#define B_  16
#define S_  1024
#define IN_ 1024
#define H_  1024
#define N1  (2*H_)          // 2048 output cols of GEMM1
#define M1  (B_*S_)         // 16384 rows of GEMM1
#define K1  IN_             // 1024

// Tiling
#define BM  128
#define BN  128
#define BK  32
#define BKP 40              // padded LDS K-stride (bf16 elems): keeps b128 frag reads 16B-aligned
#define CP  130             // epilogue LDS tile col stride: 130*2/4=65 -> bank stride 1 on transposed reads

typedef __attribute__((ext_vector_type(8))) short  short8;   // 8 bf16 = 4 VGPRs (MFMA A/B frag)
typedef __attribute__((ext_vector_type(4))) float  floatx4;  // MFMA C/D frag

// fp32 -> bf16 round-to-nearest-even (bit trick; values here are small, no inf/nan)
__device__ __forceinline__ unsigned short f2bf(float f) {
    unsigned int u = __float_as_uint(f);
    u += 0x7fffu + ((u >> 16) & 1u);
    return (unsigned short)(u >> 16);
}

// ---------------------------------------------------------------------------
// GEMM1: C[m,n] = sum_k x[m,k] * W[n,k]   (m in [0,16384), n in [0,2048))
//  - stage fp32 tiles -> bf16 LDS (RNE convert in registers)
//  - epilogue: relu -> fp32 keys/vals to d_out; bf16 TRANSPOSED keysT/valsT to ws
// ---------------------------------------------------------------------------
__global__ __launch_bounds__(256) void gemm1_kernel(
    const float* __restrict__ x, const float* __restrict__ W,
    float* __restrict__ out,
    unsigned short* __restrict__ kT, unsigned short* __restrict__ vT)
{
    __shared__ unsigned short lds[BM * CP];          // 33,280 B; staging uses first 20,480 B
    unsigned short* ldsA = lds;                      // [BM][BKP]
    unsigned short* ldsB = lds + BM * BKP;           // [BN][BKP]

    const int tid  = threadIdx.x;
    const int wave = tid >> 6, lane = tid & 63;
    const int quad = lane >> 4, r = lane & 15;
    const int wm = (wave >> 1) * 64;                 // wave row origin in tile
    const int wn = (wave & 1) * 64;                  // wave col origin in tile
    const int bx = blockIdx.x;                       // n-tile (0..15)
    const int by = blockIdx.y;                       // m-tile (0..127)
    const int m0 = by * BM;
    const int n0 = bx * BN;

    floatx4 acc[4][4] = {};

    for (int kt = 0; kt < K1; kt += BK) {
        __syncthreads();
        // Stage A (x rows m0..m0+127) and B (W rows n0..n0+127), fp32->bf16.
        // 128 rows x 8 float4-chunks = 1024 chunks per operand; 256 threads -> 4 each.
#pragma unroll
        for (int i = 0; i < 4; ++i) {
            int id  = tid + 256 * i;
            int row = id >> 3, ch = id & 7;          // ch*4 floats within the 32-wide K tile
            float4 va = *(const float4*)(x + (size_t)(m0 + row) * K1 + kt + ch * 4);
            float4 vb = *(const float4*)(W + (size_t)(n0 + row) * K1 + kt + ch * 4);
            ushort4 pa = { f2bf(va.x), f2bf(va.y), f2bf(va.z), f2bf(va.w) };
            ushort4 pb = { f2bf(vb.x), f2bf(vb.y), f2bf(vb.z), f2bf(vb.w) };
            *(ushort4*)(ldsA + row * BKP + ch * 4) = pa;
            *(ushort4*)(ldsB + row * BKP + ch * 4) = pb;
        }
        __syncthreads();

        short8 af[4], bf[4];
#pragma unroll
        for (int i = 0; i < 4; ++i)
            af[i] = *(const short8*)(ldsA + (wm + i * 16 + r) * BKP + quad * 8);
#pragma unroll
        for (int j = 0; j < 4; ++j)
            bf[j] = *(const short8*)(ldsB + (wn + j * 16 + r) * BKP + quad * 8);
#pragma unroll
        for (int i = 0; i < 4; ++i)
#pragma unroll
            for (int j = 0; j < 4; ++j)
                acc[i][j] = __builtin_amdgcn_mfma_f32_16x16x32_bf16(af[i], bf[j], acc[i][j], 0, 0, 0);
    }

    // ---------------- epilogue ----------------
    __syncthreads();                                  // staging LDS now dead; reuse as ldsC
    unsigned short* ldsC = lds;                       // [BM][CP] : C[m_l][n_l] bf16 (post-relu)

    const bool isKeys = (bx < 8);
    float* outKV   = out + (isKeys ? (size_t)M1 * H_ : (size_t)2 * M1 * H_);
    const int ncol0 = isKeys ? n0 : (n0 - 1024);      // col base within the 1024-wide half

#pragma unroll
    for (int i = 0; i < 4; ++i)
#pragma unroll
        for (int j = 0; j < 4; ++j)
#pragma unroll
            for (int d = 0; d < 4; ++d) {
                int row_l = wm + i * 16 + quad * 4 + d;
                int col_l = wn + j * 16 + r;
                float v = fmaxf(acc[i][j][d], 0.0f);  // ReLU
                outKV[(size_t)(m0 + row_l) * H_ + ncol0 + col_l] = v;
                ldsC[row_l * CP + col_l] = f2bf(v);
            }
    __syncthreads();

    // Transposed bf16 write: wsT[b][h][s] ; block is fully inside one batch (1024%128==0)
    unsigned short* wsT = isKeys ? kT : vT;
    const int b  = m0 >> 10;
    const int s0 = m0 & 1023;
    unsigned short* dstBase = wsT + (size_t)b * H_ * S_ + (size_t)ncol0 * S_ + s0;
#pragma unroll
    for (int stp = 0; stp < 64; ++stp) {
        int o   = stp * 256 + tid;
        int n_l = o >> 7, m_l = o & 127;              // consecutive tid -> consecutive s (coalesced)
        dstBase[(size_t)n_l * S_ + m_l] = ldsC[m_l * CP + n_l];   // lane stride 65 banks -> conflict-free
    }
}

// ---------------------------------------------------------------------------
// GEMM2 (batched): mem[b][m,n] = sum_t keysT[b][m,t] * valsT[b][n,t]
// Both operands bf16 row-major [H][S] -> clean B^T-form MFMA GEMM.
// ---------------------------------------------------------------------------
__global__ __launch_bounds__(256) void gemm2_kernel(
    const unsigned short* __restrict__ kT, const unsigned short* __restrict__ vT,
    float* __restrict__ mem)
{
    __shared__ unsigned short lds[BM * BKP * 2];     // 20,480 B
    unsigned short* ldsA = lds;
    unsigned short* ldsB = lds + BM * BKP;

    const int tid  = threadIdx.x;
    const int wave = tid >> 6, lane = tid & 63;
    const int quad = lane >> 4, r = lane & 15;
    const int wm = (wave >> 1) * 64;
    const int wn = (wave & 1) * 64;
    const int m0 = blockIdx.y * BM;
    const int n0 = blockIdx.x * BN;
    const int b  = blockIdx.z;

    const unsigned short* A  = kT + (size_t)b * H_ * S_;
    const unsigned short* Bp = vT + (size_t)b * H_ * S_;

    floatx4 acc[4][4] = {};

    for (int kt = 0; kt < S_; kt += BK) {
        __syncthreads();
        // 128 rows x 4 chunks(8 bf16 = 16B) per operand = 512 chunks; 256 threads -> 2 each
#pragma unroll
        for (int i = 0; i < 2; ++i) {
            int id  = tid + 256 * i;
            int row = id >> 2, ch = id & 3;
            *(uint4*)(ldsA + row * BKP + ch * 8) = *(const uint4*)(A  + (size_t)(m0 + row) * S_ + kt + ch * 8);
            *(uint4*)(ldsB + row * BKP + ch * 8) = *(const uint4*)(Bp + (size_t)(n0 + row) * S_ + kt + ch * 8);
        }
        __syncthreads();

        short8 af[4], bf[4];
#pragma unroll
        for (int i = 0; i < 4; ++i)
            af[i] = *(const short8*)(ldsA + (wm + i * 16 + r) * BKP + quad * 8);
#pragma unroll
        for (int j = 0; j < 4; ++j)
            bf[j] = *(const short8*)(ldsB + (wn + j * 16 + r) * BKP + quad * 8);
#pragma unroll
        for (int i = 0; i < 4; ++i)
#pragma unroll
            for (int j = 0; j < 4; ++j)
                acc[i][j] = __builtin_amdgcn_mfma_f32_16x16x32_bf16(af[i], bf[j], acc[i][j], 0, 0, 0);
    }

    float* outb = mem + (size_t)b * H_ * H_;
#pragma unroll
    for (int i = 0; i < 4; ++i)
#pragma unroll
        for (int j = 0; j < 4; ++j)
#pragma unroll
            for (int d = 0; d < 4; ++d) {
                int row_l = wm + i * 16 + quad * 4 + d;
                int col_l = wn + j * 16 + r;
                outb[(size_t)(m0 + row_l) * H_ + n0 + col_l] = acc[i][j][d];
            }
}

extern "C" void kernel_launch(void* const* d_in, const int* in_sizes, int n_in,
                              void* d_out, int out_size, void* d_ws, size_t ws_size,
                              hipStream_t stream) {
    const float* x = (const float*)d_in[0];   // [16,1024,1024] f32
    const float* W = (const float*)d_in[1];   // [2048,1024] f32
    float* out = (float*)d_out;               // mem(16M) | keys(16M) | vals(16M) f32

    // ws: keysT bf16 [B][H][S] then valsT bf16 [B][H][S]  (64 MB total)
    unsigned short* kT = (unsigned short*)d_ws;
    unsigned short* vT = kT + (size_t)B_ * H_ * S_;

    dim3 g1(N1 / BN, M1 / BM);                // (16, 128)
    gemm1_kernel<<<g1, dim3(256), 0, stream>>>(x, W, out, kT, vT);

    dim3 g2(H_ / BN, H_ / BM, B_);            // (8, 8, 16)
    gemm2_kernel<<<g2, dim3(256), 0, stream>>>(kT, vT, out);
}

// Round 2
// 380.071 us; speedup vs baseline: 1.2208x; 1.2208x over previous
//
#include <hip/hip_runtime.h>

// Problem constants
#define B_  16
#define S_  1024
#define IN_ 1024
#define H_  1024
#define N1  (2*H_)          // 2048 output cols of GEMM1
#define M1  (B_*S_)         // 16384 rows of GEMM1
#define K1  IN_             // 1024
#define XN  (M1*IN_)        // 16,777,216 elems of x
#define WN  (N1*IN_)        //  2,097,152 elems of W

// Tiling
#define BM  128
#define BN  128
#define BK  32              // bf16 elems; one row of a staged tile = 64 B (NO padding: global_load_lds)
#define CP  130             // epilogue LDS col stride: transposed reads land on consecutive banks

typedef __attribute__((ext_vector_type(8))) short  short8;   // 8 bf16 = 4 VGPRs (MFMA A/B frag)
typedef __attribute__((ext_vector_type(4))) float  floatx4;  // MFMA C/D frag

// fp32 -> bf16 round-to-nearest-even
__device__ __forceinline__ unsigned short f2bf(float f) {
    unsigned int u = __float_as_uint(f);
    u += 0x7fffu + ((u >> 16) & 1u);
    return (unsigned short)(u >> 16);
}

// async global->LDS, 16 B per lane; LDS dst is wave-uniform base + lane*16
#define GLDS16(gp, lp) __builtin_amdgcn_global_load_lds(                      \
    (const __attribute__((address_space(1))) void*)(gp),                      \
    (__attribute__((address_space(3))) void*)(lp), 16, 0, 0)

// ---------------------------------------------------------------------------
// convert: fp32 -> bf16 for x and W (memory-bound). Block-uniform branch:
// XN is an exact multiple of 2048 (= elems per block).
// ---------------------------------------------------------------------------
__global__ __launch_bounds__(256) void convert_kernel(
    const float* __restrict__ x, const float* __restrict__ W,
    unsigned short* __restrict__ xb, unsigned short* __restrict__ Wb)
{
    size_t i = ((size_t)blockIdx.x * 256 + threadIdx.x) * 8;
    const float* src;
    unsigned short* dst;
    if (i < (size_t)XN) { src = x + i; dst = xb + i; }
    else                { src = W + (i - XN); dst = Wb + (i - XN); }
    float4 a = *(const float4*)(src);
    float4 b = *(const float4*)(src + 4);
    ushort4 p = { f2bf(a.x), f2bf(a.y), f2bf(a.z), f2bf(a.w) };
    ushort4 q = { f2bf(b.x), f2bf(b.y), f2bf(b.z), f2bf(b.w) };
    *(ushort4*)(dst)     = p;
    *(ushort4*)(dst + 4) = q;
}

// ---------------------------------------------------------------------------
// GEMM1: C[m,n] = sum_k xb[m,k] * Wb[n,k]  (bf16 in, m97-style global_load_lds)
// Epilogue: relu -> fp32 keys/vals to d_out; bf16 TRANSPOSED keysT/valsT to ws.
// LDS chunk swizzle: slot (row,c) holds global chunk (row, c ^ ((row>>1)&3))
// -> ds_read_b128 frag loads are 2-way-bank-only (free), global stays coalesced.
// ---------------------------------------------------------------------------
__global__ __launch_bounds__(256) void gemm1_kernel(
    const unsigned short* __restrict__ xb, const unsigned short* __restrict__ Wb,
    float* __restrict__ out,
    unsigned short* __restrict__ kT, unsigned short* __restrict__ vT)
{
    __shared__ unsigned short lds[BM * CP];          // 33,280 B; staging uses first 16,384 B
    unsigned short* ldsA = lds;                      // [128][32] bf16, row stride 64 B
    unsigned short* ldsB = lds + BM * BK;            // [128][32]

    const int tid  = threadIdx.x;
    const int wave = tid >> 6, lane = tid & 63;
    const int quad = lane >> 4, r = lane & 15;
    const int wm = (wave >> 1) * 64;
    const int wn = (wave & 1) * 64;
    const int m0 = blockIdx.y * BM;
    const int n0 = blockIdx.x * BN;

    const unsigned short* Ag = xb + (size_t)m0 * K1;
    const unsigned short* Bg = Wb + (size_t)n0 * K1;

    const int cq = quad ^ ((r >> 1) & 3);            // read-side chunk un-swizzle

    floatx4 acc[4][4] = {};

    for (int kt = 0; kt < K1; kt += BK) {
        __syncthreads();
#pragma unroll
        for (int t = 0; t < 2; ++t) {
            int seg  = t * 4 + wave;                 // wave-uniform
            int slot = seg * 64 + lane;
            int row  = slot >> 2, c = slot & 3;
            int cs   = c ^ ((row >> 1) & 3);
            GLDS16(Ag + (size_t)row * K1 + kt + cs * 8, ldsA + seg * 512);
            GLDS16(Bg + (size_t)row * K1 + kt + cs * 8, ldsB + seg * 512);
        }
        __syncthreads();

        short8 af[4], bfr[4];
#pragma unroll
        for (int i = 0; i < 4; ++i)
            af[i]  = *(const short8*)(ldsA + (wm + i * 16 + r) * BK + cq * 8);
#pragma unroll
        for (int j = 0; j < 4; ++j)
            bfr[j] = *(const short8*)(ldsB + (wn + j * 16 + r) * BK + cq * 8);
#pragma unroll
        for (int i = 0; i < 4; ++i)
#pragma unroll
            for (int j = 0; j < 4; ++j)
                acc[i][j] = __builtin_amdgcn_mfma_f32_16x16x32_bf16(af[i], bfr[j], acc[i][j], 0, 0, 0);
    }

    // ---------------- epilogue ----------------
    __syncthreads();                                  // staging LDS now dead; reuse as ldsC
    unsigned short* ldsC = lds;                       // [BM][CP] bf16 post-relu

    const bool isKeys = (blockIdx.x < 8);
    float* outKV    = out + (isKeys ? (size_t)M1 * H_ : (size_t)2 * M1 * H_);
    const int ncol0 = isKeys ? n0 : (n0 - 1024);

#pragma unroll
    for (int i = 0; i < 4; ++i)
#pragma unroll
        for (int j = 0; j < 4; ++j)
#pragma unroll
            for (int d = 0; d < 4; ++d) {
                int row_l = wm + i * 16 + quad * 4 + d;
                int col_l = wn + j * 16 + r;
                float v = fmaxf(acc[i][j][d], 0.0f);
                outKV[(size_t)(m0 + row_l) * H_ + ncol0 + col_l] = v;
                ldsC[row_l * CP + col_l] = f2bf(v);
            }
    __syncthreads();

    unsigned short* wsT = isKeys ? kT : vT;
    const int b  = m0 >> 10;
    const int s0 = m0 & 1023;
    unsigned short* dstBase = wsT + (size_t)b * H_ * S_ + (size_t)ncol0 * S_ + s0;
#pragma unroll
    for (int stp = 0; stp < 64; ++stp) {
        int o   = stp * 256 + tid;
        int n_l = o >> 7, m_l = o & 127;              // consecutive tid -> consecutive s (coalesced)
        dstBase[(size_t)n_l * S_ + m_l] = ldsC[m_l * CP + n_l];   // bank stride 1 on reads
    }
}

// ---------------------------------------------------------------------------
// GEMM2 (batched): mem[b][m,n] = sum_t keysT[b][m,t] * valsT[b][n,t]
// Same m97-style K-loop on bf16 [H][S] row-major operands.
// ---------------------------------------------------------------------------
__global__ __launch_bounds__(256) void gemm2_kernel(
    const unsigned short* __restrict__ kT, const unsigned short* __restrict__ vT,
    float* __restrict__ mem)
{
    __shared__ unsigned short lds[BM * BK * 2];      // 16,384 B
    unsigned short* ldsA = lds;
    unsigned short* ldsB = lds + BM * BK;

    const int tid  = threadIdx.x;
    const int wave = tid >> 6, lane = tid & 63;
    const int quad = lane >> 4, r = lane & 15;
    const int wm = (wave >> 1) * 64;
    const int wn = (wave & 1) * 64;
    const int m0 = blockIdx.y * BM;
    const int n0 = blockIdx.x * BN;
    const int b  = blockIdx.z;

    const unsigned short* Ag = kT + (size_t)b * H_ * S_ + (size_t)m0 * S_;
    const unsigned short* Bg = vT + (size_t)b * H_ * S_ + (size_t)n0 * S_;

    const int cq = quad ^ ((r >> 1) & 3);

    floatx4 acc[4][4] = {};

    for (int kt = 0; kt < S_; kt += BK) {
        __syncthreads();
#pragma unroll
        for (int t = 0; t < 2; ++t) {
            int seg  = t * 4 + wave;
            int slot = seg * 64 + lane;
            int row  = slot >> 2, c = slot & 3;
            int cs   = c ^ ((row >> 1) & 3);
            GLDS16(Ag + (size_t)row * S_ + kt + cs * 8, ldsA + seg * 512);
            GLDS16(Bg + (size_t)row * S_ + kt + cs * 8, ldsB + seg * 512);
        }
        __syncthreads();

        short8 af[4], bfr[4];
#pragma unroll
        for (int i = 0; i < 4; ++i)
            af[i]  = *(const short8*)(ldsA + (wm + i * 16 + r) * BK + cq * 8);
#pragma unroll
        for (int j = 0; j < 4; ++j)
            bfr[j] = *(const short8*)(ldsB + (wn + j * 16 + r) * BK + cq * 8);
#pragma unroll
        for (int i = 0; i < 4; ++i)
#pragma unroll
            for (int j = 0; j < 4; ++j)
                acc[i][j] = __builtin_amdgcn_mfma_f32_16x16x32_bf16(af[i], bfr[j], acc[i][j], 0, 0, 0);
    }

    float* outb = mem + (size_t)b * H_ * H_;
#pragma unroll
    for (int i = 0; i < 4; ++i)
#pragma unroll
        for (int j = 0; j < 4; ++j)
#pragma unroll
            for (int d = 0; d < 4; ++d) {
                int row_l = wm + i * 16 + quad * 4 + d;
                int col_l = wn + j * 16 + r;
                outb[(size_t)(m0 + row_l) * H_ + n0 + col_l] = acc[i][j][d];
            }
}

extern "C" void kernel_launch(void* const* d_in, const int* in_sizes, int n_in,
                              void* d_out, int out_size, void* d_ws, size_t ws_size,
                              hipStream_t stream) {
    const float* x = (const float*)d_in[0];   // [16,1024,1024] f32
    const float* W = (const float*)d_in[1];   // [2048,1024] f32
    float* out = (float*)d_out;               // mem(16M) | keys(16M) | vals(16M) f32

    // Stash bf16 inputs in d_out's mem region (64 MB; not written until gemm2)
    unsigned short* xb = (unsigned short*)d_out;            // 33.5 MB
    unsigned short* Wb = xb + (size_t)XN;                   //  4.2 MB (total 37.7 < 64 MB)

    // ws: keysT/valsT bf16 [B][H][S] (64 MB)
    unsigned short* kT = (unsigned short*)d_ws;
    unsigned short* vT = kT + (size_t)B_ * H_ * S_;

    convert_kernel<<<dim3((XN + WN) / 2048), dim3(256), 0, stream>>>(x, W, xb, Wb);

    dim3 g1(N1 / BN, M1 / BM);                // (16, 128)
    gemm1_kernel<<<g1, dim3(256), 0, stream>>>(xb, Wb, out, kT, vT);

    dim3 g2(H_ / BN, H_ / BM, B_);            // (8, 8, 16)
    gemm2_kernel<<<g2, dim3(256), 0, stream>>>(kT, vT, out);
}